// Round 7
// baseline (327.570 us; speedup 1.0000x reference)
//
#include <hip/hip_runtime.h>
#include <math.h>

typedef __attribute__((ext_vector_type(8))) short short8;
typedef __attribute__((ext_vector_type(4))) float f32x4;
typedef unsigned short ushort_t;

#define TSEQ   4096
#define NBATCH 4
#define DMODEL 768
#define HS     64
#define KSPLIT 4

static __device__ __forceinline__ ushort_t f2bf(float f) {
  union { float f; unsigned u; } v; v.f = f;
  unsigned r = v.u + 0x7fffu + ((v.u >> 16) & 1u);   // RNE
  return (ushort_t)(r >> 16);
}
static __device__ __forceinline__ float bf2f(ushort_t u) {
  union { unsigned u; float f; } v; v.u = ((unsigned)u) << 16; return v.f;
}

#define MFMA16(a,b,c) __builtin_amdgcn_mfma_f32_16x16x32_bf16((a),(b),(c),0,0,0)

// ---------------- W prep (coalesced LDS transpose) + counter zero ----------
// grid 36 = 3 mats x 12 k-chunks of 64.  Wt[n'=m*64+n][k] bf16.
// Block 0 also zeroes the split-k semaphores (ws is re-poisoned each bench
// iteration, so in-pipeline zeroing is mandatory; wprep precedes attn_part
// in stream order).
__global__ __launch_bounds__(256) void wprep(
    const float* __restrict__ Wq, const float* __restrict__ Wk,
    const float* __restrict__ Wv, ushort_t* __restrict__ Wt, int* __restrict__ cnt)
{
  __shared__ float lds[64 * 65];
  const int tid = threadIdx.x;
  if (blockIdx.x == 0) cnt[tid] = 0;            // 256 = NBATCH*64 counters
  const int m = blockIdx.x / 12, kc = blockIdx.x % 12, k0 = kc * 64;
  const float* W = (m == 0) ? Wq : (m == 1) ? Wk : Wv;
#pragma unroll
  for (int i = 0; i < 16; i++) {
    const int row = i * 4 + (tid >> 6), col = tid & 63;
    lds[row * 65 + col] = W[(size_t)(k0 + row) * HS + col];   // coalesced
  }
  __syncthreads();
#pragma unroll
  for (int i = 0; i < 16; i++) {
    const int n = i * 4 + (tid >> 6), kk = tid & 63;
    Wt[(size_t)(m * 64 + n) * DMODEL + k0 + kk] = f2bf(lds[kk * 65 + n]);
  }
}

// ---------------- QKV projection: dual-LDS double-buffered GEMM ----------
// Round-5 structure (won: 52 -> ~31 us).  Epilogue writes k and vT in
// ROW-XOR-SWIZZLED layouts (16B-block index ^= row&7) so attn_part can
// stage them with linear global_load_lds and read conflict-free.
__global__ __launch_bounds__(256, 2) void qkv_mfma(
    const float* __restrict__ x, const ushort_t* __restrict__ Wt,
    ushort_t* __restrict__ q, ushort_t* __restrict__ kO, ushort_t* __restrict__ vT)
{
  __shared__ __align__(16) ushort_t sA[2][32 * 72];    //  9.2 KB
  __shared__ __align__(16) ushort_t sB[2][192 * 64];   // 48.0 KB

  const int tid  = threadIdx.x;
  const int w    = tid >> 6;                    // wave id = col split 0..3
  const int lane = tid & 63;
  const int l16  = lane & 15, quad = lane >> 4;
  const int M0   = blockIdx.x * 32;

  // A staging role: thread t covers row t/8, k-chunk (t%8)*8 (2 float4)
  const int arow = tid >> 3, acol = (tid & 7) * 8;
  const float* ax = x + (size_t)(M0 + arow) * DMODEL + acol;

  // B staging role: pre-swizzled global k-offset (linear LDS dest + swz read)
  const int bcol_l = lane >> 3;                               // 0..7
  const int bkoff  = (((lane & 7) ^ (bcol_l & 7)) << 3);      // elems

  f32x4 acc[2][3];
#pragma unroll
  for (int mt = 0; mt < 2; mt++)
#pragma unroll
    for (int nt = 0; nt < 3; nt++) acc[mt][nt] = (f32x4){0.f, 0.f, 0.f, 0.f};

  // ---- prologue: stage tile 0 into buf 0
  {
#pragma unroll
    for (int j = 0; j < 6; j++) {
      const int colb = w * 48 + j * 8;
      __builtin_amdgcn_global_load_lds(
          (const __attribute__((address_space(1))) ushort_t*)
              (Wt + (size_t)(colb + bcol_l) * DMODEL + bkoff),
          (__attribute__((address_space(3))) ushort_t*)(&sB[0][colb * 64]),
          16, 0, 0);
    }
    const float4 f0 = *(const float4*)(ax);
    const float4 f1 = *(const float4*)(ax + 4);
    short8 p;
    p[0]=f2bf(f0.x); p[1]=f2bf(f0.y); p[2]=f2bf(f0.z); p[3]=f2bf(f0.w);
    p[4]=f2bf(f1.x); p[5]=f2bf(f1.y); p[6]=f2bf(f1.z); p[7]=f2bf(f1.w);
    *(short8*)(&sA[0][arow * 72 + acol]) = p;
  }

  for (int ks = 0; ks < DMODEL / 64; ks++) {
    const int cur = ks & 1, nxt = cur ^ 1;
    __syncthreads();          // buf[cur] ready (drains prior gll + ds_write)

    float4 f0n, f1n;
    if (ks < DMODEL / 64 - 1) {
#pragma unroll
      for (int j = 0; j < 6; j++) {
        const int colb = w * 48 + j * 8;
        __builtin_amdgcn_global_load_lds(
            (const __attribute__((address_space(1))) ushort_t*)
                (Wt + (size_t)(colb + bcol_l) * DMODEL + (ks + 1) * 64 + bkoff),
            (__attribute__((address_space(3))) ushort_t*)(&sB[nxt][colb * 64]),
            16, 0, 0);
      }
      f0n = *(const float4*)(ax + (ks + 1) * 64);
      f1n = *(const float4*)(ax + (ks + 1) * 64 + 4);
    }

    // ---- compute from buf[cur]
    const ushort_t* sAc = &sA[cur][0];
    const ushort_t* sBc = &sB[cur][0];
#pragma unroll
    for (int kc = 0; kc < 2; kc++) {
      const short8 a0 = *(const short8*)(sAc + (l16)      * 72 + kc * 32 + quad * 8);
      const short8 a1 = *(const short8*)(sAc + (16 + l16) * 72 + kc * 32 + quad * 8);
      const int kswz = (kc * 32 + quad * 8) ^ ((l16 & 7) << 3);
#pragma unroll
      for (int nt = 0; nt < 3; nt++) {
        const short8 bf =
            *(const short8*)(sBc + (w * 48 + nt * 16 + l16) * 64 + kswz);
        acc[0][nt] = MFMA16(a0, bf, acc[0][nt]);
        acc[1][nt] = MFMA16(a1, bf, acc[1][nt]);
      }
    }

    if (ks < DMODEL / 64 - 1) {          // convert + stage next A tile
      short8 p;
      p[0]=f2bf(f0n.x); p[1]=f2bf(f0n.y); p[2]=f2bf(f0n.z); p[3]=f2bf(f0n.w);
      p[4]=f2bf(f1n.x); p[5]=f2bf(f1n.y); p[6]=f2bf(f1n.z); p[7]=f2bf(f1n.w);
      *(short8*)(&sA[nxt][arow * 72 + acol]) = p;
    }
  }

  // ---- epilogue: q direct; k swizzled; v via LDS transpose, swizzled ----
#pragma unroll
  for (int mt = 0; mt < 2; mt++)
#pragma unroll
    for (int nt = 0; nt < 3; nt++) {
      const int gnt = w * 3 + nt;               // 0..11
      const int mat = gnt >> 2;                 // 0=q 1=k 2=v (wave-uniform)
      if (mat == 0) {
        const int col = (gnt & 3) * 16 + l16;
#pragma unroll
        for (int r = 0; r < 4; r++)
          q[(size_t)(M0 + mt * 16 + quad * 4 + r) * HS + col] =
              f2bf(acc[mt][nt][r] * 0.125f);
      } else if (mat == 1) {
        // k: 16B-block index of col, XOR'd with trow&7 (attn-staging swizzle)
        const int cb2 = (gnt & 3) * 2 + (l16 >> 3);
#pragma unroll
        for (int r = 0; r < 4; r++) {
          const int trow  = M0 + mt * 16 + quad * 4 + r;
          const int cphys = ((cb2 ^ (trow & 7)) << 3) | (l16 & 7);
          kO[(size_t)trow * HS + cphys] = f2bf(acc[mt][nt][r]);
        }
      }
    }
  __syncthreads();                              // K-loop LDS reads done
  float* vls = (float*)&sA[0][0];               // [32][65] fp32 = 8.3 KB
#pragma unroll
  for (int mt = 0; mt < 2; mt++)
#pragma unroll
    for (int nt = 0; nt < 3; nt++) {
      const int gnt = w * 3 + nt;
      if ((gnt >> 2) == 2) {
        const int vcol = (gnt & 3) * 16 + l16;
#pragma unroll
        for (int r = 0; r < 4; r++)
          vls[(mt * 16 + quad * 4 + r) * 65 + vcol] = acc[mt][nt][r];
      }
    }
  __syncthreads();
  const int d = tid >> 2, seg = tid & 3;        // 64 dims x 4 segs of 8 t
  short8 pk;
#pragma unroll
  for (int i = 0; i < 8; i++) pk[i] = (short)f2bf(vls[(seg * 8 + i) * 65 + d]);
  // vT: key-block within 64-chunk XOR'd with d&7 (attn-staging swizzle)
  {
    const int t0  = M0 & (TSEQ - 1);
    const int tb  = t0 & ~63;
    const int kb  = ((t0 & 63) >> 3) + seg;
    const int kbp = kb ^ (d & 7);
    *(short8*)(vT + ((size_t)(M0 >> 12) * HS + d) * TSEQ + tb + kbp * 8) = pk;
  }
}

// ---------------- attention: partial flash attention + fused split-k merge --
// Round-7: (a) LDS trimmed to exactly 40 KB (sP pitch-64 with write/read
// XOR swizzle) -> 4 blocks/CU, 16 waves/CU (was 3/12); (b) s_setprio(1)
// around both MFMA clusters (T5, attn-proven +4-7%); (c) attn_merge FUSED:
// the last-done block of each (b,jt) group merges its 64 rows inline
// (threadfence + device-scope atomicAdd semaphore), killing one kernel
// launch + its gap (launch gaps measured ~10-15us each across rounds 0-6).
__global__ __launch_bounds__(256, 4) void attn_part(
    const ushort_t* __restrict__ q, const ushort_t* __restrict__ k,
    const ushort_t* __restrict__ vT, float* __restrict__ ML,
    ushort_t* __restrict__ OP, int* __restrict__ cnt, float* __restrict__ out)
{
  __shared__ __align__(16) ushort_t sK[2][64 * 64];  // 16 KB  [key][d swz]
  __shared__ __align__(16) ushort_t sV[2][64 * 64];  // 16 KB  [d][key swz]
  __shared__ __align__(16) ushort_t sP[4][16 * 64];  //  8 KB  per-wave P swz
  __shared__ int sOld;

  const int idx  = blockIdx.x;
  const int s    = idx & 3;
  const int b    = (idx >> 2) & 3;
  const int jt   = 63 - (idx >> 4);            // descending work order
  const int tid  = threadIdx.x;
  const int w    = tid >> 6;
  const int lane = tid & 63;
  const int l16  = lane & 15, quad = lane >> 4;
  const int R0   = jt * 64 + w * 16;

  const ushort_t* qg = q  + (size_t)b * TSEQ * HS;
  const ushort_t* kg = k  + (size_t)b * TSEQ * HS;
  const ushort_t* vg = vT + (size_t)b * HS * TSEQ;

  // Q B-operand frags (q pre-scaled 1/8, unswizzled): B[k=d][n=qrow]
  const short8 qf0 = *(const short8*)(qg + (size_t)(R0 + l16) * HS +      quad * 8);
  const short8 qf1 = *(const short8*)(qg + (size_t)(R0 + l16) * HS + 32 + quad * 8);

  f32x4 o[4];
#pragma unroll
  for (int dt = 0; dt < 4; dt++) o[dt] = (f32x4){0.f, 0.f, 0.f, 0.f};
  float mrow = -INFINITY, lrow = 0.f;          // per-lane qrow = R0 + l16

  const int nkt = jt + 1;                      // 64-key chunks incl. diagonal
  const int srow = lane >> 3;                  // staging: 8 rows/issue
  const int scol = (lane & 7) * 8;

  int kt = s, cur = 0;
  if (kt < nkt) {                              // prologue: stage chunk kt->buf0
    const int k0 = kt * 64;
#pragma unroll
    for (int j = 0; j < 2; j++) {
      const int r0 = w * 16 + j * 8;
      __builtin_amdgcn_global_load_lds(
          (const __attribute__((address_space(1))) ushort_t*)
              (kg + (size_t)(k0 + r0 + srow) * HS + scol),
          (__attribute__((address_space(3))) ushort_t*)(&sK[0][r0 * 64]),
          16, 0, 0);
      __builtin_amdgcn_global_load_lds(
          (const __attribute__((address_space(1))) ushort_t*)
              (vg + (size_t)(r0 + srow) * TSEQ + k0 + scol),
          (__attribute__((address_space(3))) ushort_t*)(&sV[0][r0 * 64]),
          16, 0, 0);
    }
  }
  for (; kt < nkt; kt += KSPLIT) {
    const int k0 = kt * 64;
    __syncthreads();                           // buf[cur] staged & prior reads done
    if (kt + KSPLIT < nkt) {                   // async stage next chunk
      const int kn = (kt + KSPLIT) * 64;
#pragma unroll
      for (int j = 0; j < 2; j++) {
        const int r0 = w * 16 + j * 8;
        __builtin_amdgcn_global_load_lds(
            (const __attribute__((address_space(1))) ushort_t*)
                (kg + (size_t)(kn + r0 + srow) * HS + scol),
            (__attribute__((address_space(3))) ushort_t*)(&sK[cur ^ 1][r0 * 64]),
            16, 0, 0);
        __builtin_amdgcn_global_load_lds(
            (const __attribute__((address_space(1))) ushort_t*)
                (vg + (size_t)(r0 + srow) * TSEQ + kn + scol),
            (__attribute__((address_space(3))) ushort_t*)(&sV[cur ^ 1][r0 * 64]),
            16, 0, 0);
      }
    }
    const ushort_t* sKc = &sK[cur][0];
    const ushort_t* sVc = &sV[cur][0];
    const int sw = (l16 & 7) << 3;             // row-XOR (elems; 16B blocks)

    // ---- S^T = K Q^T : C[key = ct*16+quad*4+r][qrow = l16] ----
    f32x4 sT[4];
    __builtin_amdgcn_s_setprio(1);
#pragma unroll
    for (int ct = 0; ct < 4; ct++) {
      sT[ct] = (f32x4){0.f, 0.f, 0.f, 0.f};
      const short8 kfa = *(const short8*)(sKc + (ct * 16 + l16) * 64 + ((quad * 8)      ^ sw));
      const short8 kfb = *(const short8*)(sKc + (ct * 16 + l16) * 64 + ((32 + quad * 8) ^ sw));
      sT[ct] = MFMA16(kfa, qf0, sT[ct]);
      sT[ct] = MFMA16(kfb, qf1, sT[ct]);
    }
    __builtin_amdgcn_s_setprio(0);
    if (k0 + 63 > R0) {                        // causal mask, diagonal only
      const int qrow = R0 + l16;
#pragma unroll
      for (int ct = 0; ct < 4; ct++)
#pragma unroll
        for (int r = 0; r < 4; r++)
          sT[ct][r] = (k0 + ct * 16 + quad * 4 + r <= qrow) ? sT[ct][r] : -INFINITY;
    }
    // ---- online softmax (per-lane row; 2 cross-quad shuffles) ----
    float tm = -INFINITY;
#pragma unroll
    for (int ct = 0; ct < 4; ct++)
#pragma unroll
      for (int r = 0; r < 4; r++) tm = fmaxf(tm, sT[ct][r]);
    tm = fmaxf(tm, __shfl_xor(tm, 16));
    tm = fmaxf(tm, __shfl_xor(tm, 32));
    const float mn = fmaxf(mrow, tm);
    const float al = __expf(mrow - mn);
    mrow = mn;
    float ps = 0.f;
#pragma unroll
    for (int ct = 0; ct < 4; ct++)
#pragma unroll
      for (int r = 0; r < 4; r++) { sT[ct][r] = __expf(sT[ct][r] - mn); ps += sT[ct][r]; }
    ps += __shfl_xor(ps, 16);
    ps += __shfl_xor(ps, 32);
    lrow = lrow * al + ps;
    // ---- P -> LDS (pitch 64, XOR-swizzled both sides), O rescale, PV ----
    ushort_t* Pw = &sP[w][0];
#pragma unroll
    for (int ct = 0; ct < 4; ct++) {
      ushort4 pk;
      pk.x = f2bf(sT[ct][0]); pk.y = f2bf(sT[ct][1]);
      pk.z = f2bf(sT[ct][2]); pk.w = f2bf(sT[ct][3]);
      const int pb = (ct * 2 + (quad >> 1)) ^ (l16 & 7);   // phys 8-elem block
      *(ushort4*)(Pw + l16 * 64 + pb * 8 + (quad & 1) * 4) = pk;
    }
    float alo[4];
#pragma unroll
    for (int r = 0; r < 4; r++) alo[r] = __shfl(al, quad * 4 + r);
#pragma unroll
    for (int dt = 0; dt < 4; dt++)
#pragma unroll
      for (int r = 0; r < 4; r++) o[dt][r] *= alo[r];
    const short8 pf0 = *(const short8*)(Pw + l16 * 64 + (((quad)     ^ (l16 & 7)) << 3));
    const short8 pf1 = *(const short8*)(Pw + l16 * 64 + (((4 + quad) ^ (l16 & 7)) << 3));
    __builtin_amdgcn_s_setprio(1);
#pragma unroll
    for (int dt = 0; dt < 4; dt++) {
      const short8 vfa = *(const short8*)(sVc + (dt * 16 + l16) * 64 + ((quad * 8)      ^ sw));
      const short8 vfb = *(const short8*)(sVc + (dt * 16 + l16) * 64 + ((32 + quad * 8) ^ sw));
      o[dt] = MFMA16(pf0, vfa, o[dt]);
      o[dt] = MFMA16(pf1, vfb, o[dt]);
    }
    __builtin_amdgcn_s_setprio(0);
    cur ^= 1;
  }

  // ---- write partials: ML fp32 [B][KSPLIT][T][2], OP bf16 [B][KSPLIT][T][64] ----
  const size_t base = ((size_t)(b * KSPLIT + s) * TSEQ);
  if (quad == 0) {
    ML[(base + R0 + l16) * 2 + 0] = mrow;
    ML[(base + R0 + l16) * 2 + 1] = lrow;
  }
#pragma unroll
  for (int dt = 0; dt < 4; dt++)
#pragma unroll
    for (int r = 0; r < 4; r++)
      OP[(base + R0 + quad * 4 + r) * HS + dt * 16 + l16] = f2bf(o[dt][r]);

  // ---- fused split-k merge: last-done block of (b,jt) merges 64 rows ----
  __threadfence();                              // release partials (device)
  if (tid == 0) sOld = atomicAdd(&cnt[b * 64 + jt], 1);
  __syncthreads();
  if (sOld == KSPLIT - 1) {
    __threadfence();                            // acquire others' partials
    const int rr = tid >> 2, d0 = (tid & 3) * 16;
    const int row = jt * 64 + rr;
    float m4[KSPLIT], l4[KSPLIT];
    float M = -INFINITY;
#pragma unroll
    for (int ss = 0; ss < KSPLIT; ss++) {
      const size_t i = ((size_t)(b * KSPLIT + ss) * TSEQ + row);
      m4[ss] = ML[i * 2]; l4[ss] = ML[i * 2 + 1];
      M = fmaxf(M, m4[ss]);
    }
    float den = 0.f;
    float n0 = 0.f, n1 = 0.f, n2 = 0.f, n3 = 0.f, n4 = 0.f, n5 = 0.f, n6 = 0.f, n7 = 0.f;
    float n8 = 0.f, n9 = 0.f, nA = 0.f, nB = 0.f, nC = 0.f, nD = 0.f, nE = 0.f, nF = 0.f;
#pragma unroll
    for (int ss = 0; ss < KSPLIT; ss++) {
      const float a = __expf(m4[ss] - M);       // zero-trip split: weight 0
      den += l4[ss] * a;
      const size_t i = ((size_t)(b * KSPLIT + ss) * TSEQ + row);
      const ushort4 u0 = *(const ushort4*)(OP + i * HS + d0);
      const ushort4 u1 = *(const ushort4*)(OP + i * HS + d0 + 4);
      const ushort4 u2 = *(const ushort4*)(OP + i * HS + d0 + 8);
      const ushort4 u3 = *(const ushort4*)(OP + i * HS + d0 + 12);
      n0 += a * bf2f(u0.x); n1 += a * bf2f(u0.y); n2 += a * bf2f(u0.z); n3 += a * bf2f(u0.w);
      n4 += a * bf2f(u1.x); n5 += a * bf2f(u1.y); n6 += a * bf2f(u1.z); n7 += a * bf2f(u1.w);
      n8 += a * bf2f(u2.x); n9 += a * bf2f(u2.y); nA += a * bf2f(u2.z); nB += a * bf2f(u2.w);
      nC += a * bf2f(u3.x); nD += a * bf2f(u3.y); nE += a * bf2f(u3.z); nF += a * bf2f(u3.w);
    }
    const float inv = 1.f / den;
    float* op = out + ((size_t)(b * TSEQ + row)) * HS + d0;
    *(float4*)(op)      = make_float4(n0 * inv, n1 * inv, n2 * inv, n3 * inv);
    *(float4*)(op + 4)  = make_float4(n4 * inv, n5 * inv, n6 * inv, n7 * inv);
    *(float4*)(op + 8)  = make_float4(n8 * inv, n9 * inv, nA * inv, nB * inv);
    *(float4*)(op + 12) = make_float4(nC * inv, nD * inv, nE * inv, nF * inv);
  }
}

extern "C" void kernel_launch(void* const* d_in, const int* in_sizes, int n_in,
                              void* d_out, int out_size, void* d_ws, size_t ws_size,
                              hipStream_t stream) {
  const float* x  = (const float*)d_in[0];
  const float* Wq = (const float*)d_in[1];
  const float* Wk = (const float*)d_in[2];
  const float* Wv = (const float*)d_in[3];
  float* out = (float*)d_out;

  // ws: Wt 288K | q 2M | k 2M | vT 2M | ML 512K | OP 8M | cnt 1K  (~15.5 MB)
  char* ws = (char*)d_ws;
  ushort_t* Wt = (ushort_t*)ws;
  ushort_t* qb = (ushort_t*)(ws + 294912);
  ushort_t* kb = (ushort_t*)(ws + 294912 + 2097152);
  ushort_t* vb = (ushort_t*)(ws + 294912 + 2 * 2097152);
  float*    ml = (float*)   (ws + 294912 + 3 * 2097152);
  ushort_t* op = (ushort_t*)(ws + 294912 + 3 * 2097152 + 524288);
  int*      cn = (int*)     (ws + 294912 + 3 * 2097152 + 524288 + 8388608);

  wprep<<<36, 256, 0, stream>>>(Wq, Wk, Wv, Wt, cn);
  qkv_mfma<<<(NBATCH * TSEQ) / 32, 256, 0, stream>>>(x, Wt, qb, kb, vb);
  attn_part<<<64 * NBATCH * KSPLIT, 256, 0, stream>>>(qb, kb, vb, ml, op, cn, out);
}

// Round 8
// 128.966 us; speedup vs baseline: 2.5400x; 2.5400x over previous
//
#include <hip/hip_runtime.h>
#include <math.h>

typedef __attribute__((ext_vector_type(8))) short short8;
typedef __attribute__((ext_vector_type(4))) float f32x4;
typedef unsigned short ushort_t;

#define TSEQ   4096
#define NBATCH 4
#define DMODEL 768
#define HS     64
#define KSPLIT 4

static __device__ __forceinline__ ushort_t f2bf(float f) {
  union { float f; unsigned u; } v; v.f = f;
  unsigned r = v.u + 0x7fffu + ((v.u >> 16) & 1u);   // RNE
  return (ushort_t)(r >> 16);
}
static __device__ __forceinline__ float bf2f(ushort_t u) {
  union { unsigned u; float f; } v; v.u = ((unsigned)u) << 16; return v.f;
}

#define MFMA16(a,b,c) __builtin_amdgcn_mfma_f32_16x16x32_bf16((a),(b),(c),0,0,0)

// ---------------- W prep (coalesced LDS transpose) ----------------
// grid 36 = 3 mats x 12 k-chunks of 64.  Wt[n'=m*64+n][k] bf16.
__global__ __launch_bounds__(256) void wprep(
    const float* __restrict__ Wq, const float* __restrict__ Wk,
    const float* __restrict__ Wv, ushort_t* __restrict__ Wt)
{
  __shared__ float lds[64 * 65];
  const int m = blockIdx.x / 12, kc = blockIdx.x % 12, k0 = kc * 64;
  const float* W = (m == 0) ? Wq : (m == 1) ? Wk : Wv;
  const int tid = threadIdx.x;
#pragma unroll
  for (int i = 0; i < 16; i++) {
    const int row = i * 4 + (tid >> 6), col = tid & 63;
    lds[row * 65 + col] = W[(size_t)(k0 + row) * HS + col];   // coalesced
  }
  __syncthreads();
#pragma unroll
  for (int i = 0; i < 16; i++) {
    const int n = i * 4 + (tid >> 6), kk = tid & 63;
    Wt[(size_t)(m * 64 + n) * DMODEL + k0 + kk] = f2bf(lds[kk * 65 + n]);
  }
}

// ---------------- QKV projection: dual-LDS double-buffered GEMM ----------
// Round-5 structure (won: 52 -> ~31 us).  Epilogue writes k and vT in
// ROW-XOR-SWIZZLED layouts (16B-block index ^= row&7) so attn_part can
// stage them with linear global_load_lds and read conflict-free.
__global__ __launch_bounds__(256, 2) void qkv_mfma(
    const float* __restrict__ x, const ushort_t* __restrict__ Wt,
    ushort_t* __restrict__ q, ushort_t* __restrict__ kO, ushort_t* __restrict__ vT)
{
  __shared__ __align__(16) ushort_t sA[2][32 * 72];    //  9.2 KB
  __shared__ __align__(16) ushort_t sB[2][192 * 64];   // 48.0 KB

  const int tid  = threadIdx.x;
  const int w    = tid >> 6;                    // wave id = col split 0..3
  const int lane = tid & 63;
  const int l16  = lane & 15, quad = lane >> 4;
  const int M0   = blockIdx.x * 32;

  // A staging role: thread t covers row t/8, k-chunk (t%8)*8 (2 float4)
  const int arow = tid >> 3, acol = (tid & 7) * 8;
  const float* ax = x + (size_t)(M0 + arow) * DMODEL + acol;

  // B staging role: pre-swizzled global k-offset (linear LDS dest + swz read)
  const int bcol_l = lane >> 3;                               // 0..7
  const int bkoff  = (((lane & 7) ^ (bcol_l & 7)) << 3);      // elems

  f32x4 acc[2][3];
#pragma unroll
  for (int mt = 0; mt < 2; mt++)
#pragma unroll
    for (int nt = 0; nt < 3; nt++) acc[mt][nt] = (f32x4){0.f, 0.f, 0.f, 0.f};

  // ---- prologue: stage tile 0 into buf 0
  {
#pragma unroll
    for (int j = 0; j < 6; j++) {
      const int colb = w * 48 + j * 8;
      __builtin_amdgcn_global_load_lds(
          (const __attribute__((address_space(1))) ushort_t*)
              (Wt + (size_t)(colb + bcol_l) * DMODEL + bkoff),
          (__attribute__((address_space(3))) ushort_t*)(&sB[0][colb * 64]),
          16, 0, 0);
    }
    const float4 f0 = *(const float4*)(ax);
    const float4 f1 = *(const float4*)(ax + 4);
    short8 p;
    p[0]=f2bf(f0.x); p[1]=f2bf(f0.y); p[2]=f2bf(f0.z); p[3]=f2bf(f0.w);
    p[4]=f2bf(f1.x); p[5]=f2bf(f1.y); p[6]=f2bf(f1.z); p[7]=f2bf(f1.w);
    *(short8*)(&sA[0][arow * 72 + acol]) = p;
  }

  for (int ks = 0; ks < DMODEL / 64; ks++) {
    const int cur = ks & 1, nxt = cur ^ 1;
    __syncthreads();          // buf[cur] ready (drains prior gll + ds_write)

    float4 f0n, f1n;
    if (ks < DMODEL / 64 - 1) {
#pragma unroll
      for (int j = 0; j < 6; j++) {
        const int colb = w * 48 + j * 8;
        __builtin_amdgcn_global_load_lds(
            (const __attribute__((address_space(1))) ushort_t*)
                (Wt + (size_t)(colb + bcol_l) * DMODEL + (ks + 1) * 64 + bkoff),
            (__attribute__((address_space(3))) ushort_t*)(&sB[nxt][colb * 64]),
            16, 0, 0);
      }
      f0n = *(const float4*)(ax + (ks + 1) * 64);
      f1n = *(const float4*)(ax + (ks + 1) * 64 + 4);
    }

    // ---- compute from buf[cur]
    const ushort_t* sAc = &sA[cur][0];
    const ushort_t* sBc = &sB[cur][0];
#pragma unroll
    for (int kc = 0; kc < 2; kc++) {
      const short8 a0 = *(const short8*)(sAc + (l16)      * 72 + kc * 32 + quad * 8);
      const short8 a1 = *(const short8*)(sAc + (16 + l16) * 72 + kc * 32 + quad * 8);
      const int kswz = (kc * 32 + quad * 8) ^ ((l16 & 7) << 3);
#pragma unroll
      for (int nt = 0; nt < 3; nt++) {
        const short8 bf =
            *(const short8*)(sBc + (w * 48 + nt * 16 + l16) * 64 + kswz);
        acc[0][nt] = MFMA16(a0, bf, acc[0][nt]);
        acc[1][nt] = MFMA16(a1, bf, acc[1][nt]);
      }
    }

    if (ks < DMODEL / 64 - 1) {          // convert + stage next A tile
      short8 p;
      p[0]=f2bf(f0n.x); p[1]=f2bf(f0n.y); p[2]=f2bf(f0n.z); p[3]=f2bf(f0n.w);
      p[4]=f2bf(f1n.x); p[5]=f2bf(f1n.y); p[6]=f2bf(f1n.z); p[7]=f2bf(f1n.w);
      *(short8*)(&sA[nxt][arow * 72 + acol]) = p;
    }
  }

  // ---- epilogue: q direct; k swizzled; v via LDS transpose, swizzled ----
#pragma unroll
  for (int mt = 0; mt < 2; mt++)
#pragma unroll
    for (int nt = 0; nt < 3; nt++) {
      const int gnt = w * 3 + nt;               // 0..11
      const int mat = gnt >> 2;                 // 0=q 1=k 2=v (wave-uniform)
      if (mat == 0) {
        const int col = (gnt & 3) * 16 + l16;
#pragma unroll
        for (int r = 0; r < 4; r++)
          q[(size_t)(M0 + mt * 16 + quad * 4 + r) * HS + col] =
              f2bf(acc[mt][nt][r] * 0.125f);
      } else if (mat == 1) {
        // k: 16B-block index of col, XOR'd with trow&7 (attn-staging swizzle)
        const int cb2 = (gnt & 3) * 2 + (l16 >> 3);
#pragma unroll
        for (int r = 0; r < 4; r++) {
          const int trow  = M0 + mt * 16 + quad * 4 + r;
          const int cphys = ((cb2 ^ (trow & 7)) << 3) | (l16 & 7);
          kO[(size_t)trow * HS + cphys] = f2bf(acc[mt][nt][r]);
        }
      }
    }
  __syncthreads();                              // K-loop LDS reads done
  float* vls = (float*)&sA[0][0];               // [32][65] fp32 = 8.3 KB
#pragma unroll
  for (int mt = 0; mt < 2; mt++)
#pragma unroll
    for (int nt = 0; nt < 3; nt++) {
      const int gnt = w * 3 + nt;
      if ((gnt >> 2) == 2) {
        const int vcol = (gnt & 3) * 16 + l16;
#pragma unroll
        for (int r = 0; r < 4; r++)
          vls[(mt * 16 + quad * 4 + r) * 65 + vcol] = acc[mt][nt][r];
      }
    }
  __syncthreads();
  const int d = tid >> 2, seg = tid & 3;        // 64 dims x 4 segs of 8 t
  short8 pk;
#pragma unroll
  for (int i = 0; i < 8; i++) pk[i] = (short)f2bf(vls[(seg * 8 + i) * 65 + d]);
  // vT: key-block within 64-chunk XOR'd with d&7 (attn-staging swizzle)
  {
    const int t0  = M0 & (TSEQ - 1);
    const int tb  = t0 & ~63;
    const int kb  = ((t0 & 63) >> 3) + seg;
    const int kbp = kb ^ (d & 7);
    *(short8*)(vT + ((size_t)(M0 >> 12) * HS + d) * TSEQ + tb + kbp * 8) = pk;
  }
}

// ---------------- attention pass 1: partial flash attention ----------------
// Round-8: round-7's fused merge REVERTED -- its __threadfence (device-scope
// L2 writeback/invalidate x1024 blocks) caused an L2-invalidate storm: every
// block's K/V cache evicted repeatedly, attn 41 -> 257 us with all pipes idle.
// Kept from round 7 (de-confounded, both bounded + mechanism-understood):
// (a) sP pitch-64 XOR-swizzled -> LDS exactly 40960 B; 4 x 40960 = 160 KiB
//     exactly -> 4 blocks/CU, 16 waves/CU (was 3/12);
// (b) s_setprio(1) around both MFMA clusters (T5, attn-proven +4-7%).
__global__ __launch_bounds__(256, 4) void attn_part(
    const ushort_t* __restrict__ q, const ushort_t* __restrict__ k,
    const ushort_t* __restrict__ vT, float* __restrict__ ML, ushort_t* __restrict__ OP)
{
  __shared__ __align__(16) ushort_t sK[2][64 * 64];  // 16 KB  [key][d swz]
  __shared__ __align__(16) ushort_t sV[2][64 * 64];  // 16 KB  [d][key swz]
  __shared__ __align__(16) ushort_t sP[4][16 * 64];  //  8 KB  per-wave P swz

  const int idx  = blockIdx.x;
  const int s    = idx & 3;
  const int b    = (idx >> 2) & 3;
  const int jt   = 63 - (idx >> 4);            // descending work order
  const int tid  = threadIdx.x;
  const int w    = tid >> 6;
  const int lane = tid & 63;
  const int l16  = lane & 15, quad = lane >> 4;
  const int R0   = jt * 64 + w * 16;

  const ushort_t* qg = q  + (size_t)b * TSEQ * HS;
  const ushort_t* kg = k  + (size_t)b * TSEQ * HS;
  const ushort_t* vg = vT + (size_t)b * HS * TSEQ;

  // Q B-operand frags (q pre-scaled 1/8, unswizzled): B[k=d][n=qrow]
  const short8 qf0 = *(const short8*)(qg + (size_t)(R0 + l16) * HS +      quad * 8);
  const short8 qf1 = *(const short8*)(qg + (size_t)(R0 + l16) * HS + 32 + quad * 8);

  f32x4 o[4];
#pragma unroll
  for (int dt = 0; dt < 4; dt++) o[dt] = (f32x4){0.f, 0.f, 0.f, 0.f};
  float mrow = -INFINITY, lrow = 0.f;          // per-lane qrow = R0 + l16

  const int nkt = jt + 1;                      // 64-key chunks incl. diagonal
  const int srow = lane >> 3;                  // staging: 8 rows/issue
  const int scol = (lane & 7) * 8;

  int kt = s, cur = 0;
  if (kt < nkt) {                              // prologue: stage chunk kt->buf0
    const int k0 = kt * 64;
#pragma unroll
    for (int j = 0; j < 2; j++) {
      const int r0 = w * 16 + j * 8;
      __builtin_amdgcn_global_load_lds(
          (const __attribute__((address_space(1))) ushort_t*)
              (kg + (size_t)(k0 + r0 + srow) * HS + scol),
          (__attribute__((address_space(3))) ushort_t*)(&sK[0][r0 * 64]),
          16, 0, 0);
      __builtin_amdgcn_global_load_lds(
          (const __attribute__((address_space(1))) ushort_t*)
              (vg + (size_t)(r0 + srow) * TSEQ + k0 + scol),
          (__attribute__((address_space(3))) ushort_t*)(&sV[0][r0 * 64]),
          16, 0, 0);
    }
  }
  for (; kt < nkt; kt += KSPLIT) {
    const int k0 = kt * 64;
    __syncthreads();                           // buf[cur] staged & prior reads done
    if (kt + KSPLIT < nkt) {                   // async stage next chunk
      const int kn = (kt + KSPLIT) * 64;
#pragma unroll
      for (int j = 0; j < 2; j++) {
        const int r0 = w * 16 + j * 8;
        __builtin_amdgcn_global_load_lds(
            (const __attribute__((address_space(1))) ushort_t*)
                (kg + (size_t)(kn + r0 + srow) * HS + scol),
            (__attribute__((address_space(3))) ushort_t*)(&sK[cur ^ 1][r0 * 64]),
            16, 0, 0);
        __builtin_amdgcn_global_load_lds(
            (const __attribute__((address_space(1))) ushort_t*)
                (vg + (size_t)(r0 + srow) * TSEQ + kn + scol),
            (__attribute__((address_space(3))) ushort_t*)(&sV[cur ^ 1][r0 * 64]),
            16, 0, 0);
      }
    }
    const ushort_t* sKc = &sK[cur][0];
    const ushort_t* sVc = &sV[cur][0];
    const int sw = (l16 & 7) << 3;             // row-XOR (elems; 16B blocks)

    // ---- S^T = K Q^T : C[key = ct*16+quad*4+r][qrow = l16] ----
    f32x4 sT[4];
    __builtin_amdgcn_s_setprio(1);
#pragma unroll
    for (int ct = 0; ct < 4; ct++) {
      sT[ct] = (f32x4){0.f, 0.f, 0.f, 0.f};
      const short8 kfa = *(const short8*)(sKc + (ct * 16 + l16) * 64 + ((quad * 8)      ^ sw));
      const short8 kfb = *(const short8*)(sKc + (ct * 16 + l16) * 64 + ((32 + quad * 8) ^ sw));
      sT[ct] = MFMA16(kfa, qf0, sT[ct]);
      sT[ct] = MFMA16(kfb, qf1, sT[ct]);
    }
    __builtin_amdgcn_s_setprio(0);
    if (k0 + 63 > R0) {                        // causal mask, diagonal only
      const int qrow = R0 + l16;
#pragma unroll
      for (int ct = 0; ct < 4; ct++)
#pragma unroll
        for (int r = 0; r < 4; r++)
          sT[ct][r] = (k0 + ct * 16 + quad * 4 + r <= qrow) ? sT[ct][r] : -INFINITY;
    }
    // ---- online softmax (per-lane row; 2 cross-quad shuffles) ----
    float tm = -INFINITY;
#pragma unroll
    for (int ct = 0; ct < 4; ct++)
#pragma unroll
      for (int r = 0; r < 4; r++) tm = fmaxf(tm, sT[ct][r]);
    tm = fmaxf(tm, __shfl_xor(tm, 16));
    tm = fmaxf(tm, __shfl_xor(tm, 32));
    const float mn = fmaxf(mrow, tm);
    const float al = __expf(mrow - mn);
    mrow = mn;
    float ps = 0.f;
#pragma unroll
    for (int ct = 0; ct < 4; ct++)
#pragma unroll
      for (int r = 0; r < 4; r++) { sT[ct][r] = __expf(sT[ct][r] - mn); ps += sT[ct][r]; }
    ps += __shfl_xor(ps, 16);
    ps += __shfl_xor(ps, 32);
    lrow = lrow * al + ps;
    // ---- P -> LDS (pitch 64, XOR-swizzled both sides), O rescale, PV ----
    ushort_t* Pw = &sP[w][0];
#pragma unroll
    for (int ct = 0; ct < 4; ct++) {
      ushort4 pk;
      pk.x = f2bf(sT[ct][0]); pk.y = f2bf(sT[ct][1]);
      pk.z = f2bf(sT[ct][2]); pk.w = f2bf(sT[ct][3]);
      const int pb = (ct * 2 + (quad >> 1)) ^ (l16 & 7);   // phys 8-elem block
      *(ushort4*)(Pw + l16 * 64 + pb * 8 + (quad & 1) * 4) = pk;
    }
    float alo[4];
#pragma unroll
    for (int r = 0; r < 4; r++) alo[r] = __shfl(al, quad * 4 + r);
#pragma unroll
    for (int dt = 0; dt < 4; dt++)
#pragma unroll
      for (int r = 0; r < 4; r++) o[dt][r] *= alo[r];
    const short8 pf0 = *(const short8*)(Pw + l16 * 64 + (((quad)     ^ (l16 & 7)) << 3));
    const short8 pf1 = *(const short8*)(Pw + l16 * 64 + (((4 + quad) ^ (l16 & 7)) << 3));
    __builtin_amdgcn_s_setprio(1);
#pragma unroll
    for (int dt = 0; dt < 4; dt++) {
      const short8 vfa = *(const short8*)(sVc + (dt * 16 + l16) * 64 + ((quad * 8)      ^ sw));
      const short8 vfb = *(const short8*)(sVc + (dt * 16 + l16) * 64 + ((32 + quad * 8) ^ sw));
      o[dt] = MFMA16(pf0, vfa, o[dt]);
      o[dt] = MFMA16(pf1, vfb, o[dt]);
    }
    __builtin_amdgcn_s_setprio(0);
    cur ^= 1;
  }

  // ---- write partials: ML fp32 [B][KSPLIT][T][2], OP bf16 [B][KSPLIT][T][64] ----
  const size_t base = ((size_t)(b * KSPLIT + s) * TSEQ);
  if (quad == 0) {
    ML[(base + R0 + l16) * 2 + 0] = mrow;
    ML[(base + R0 + l16) * 2 + 1] = lrow;
  }
#pragma unroll
  for (int dt = 0; dt < 4; dt++)
#pragma unroll
    for (int r = 0; r < 4; r++)
      OP[(base + R0 + quad * 4 + r) * HS + dt * 16 + l16] = f2bf(o[dt][r]);
}

// ---------------- attention pass 2: merge the KSPLIT partials ----------------
// grid 1024 x 256: block = 16 rows x 16 dim-groups.
__global__ __launch_bounds__(256) void attn_merge(
    const float* __restrict__ ML, const ushort_t* __restrict__ OP,
    float* __restrict__ out)
{
  const int row = blockIdx.x * 16 + (threadIdx.x >> 4);   // 0..16383
  const int b   = row >> 12, t = row & (TSEQ - 1);
  const int d0  = (threadIdx.x & 15) * 4;
  float m[KSPLIT], l[KSPLIT];
  float M = -INFINITY;
#pragma unroll
  for (int ss = 0; ss < KSPLIT; ss++) {
    const size_t i = ((size_t)(b * KSPLIT + ss) * TSEQ + t);
    m[ss] = ML[i * 2]; l[ss] = ML[i * 2 + 1];
    M = fmaxf(M, m[ss]);
  }
  float den = 0.f;
  float4 num = make_float4(0.f, 0.f, 0.f, 0.f);
#pragma unroll
  for (int ss = 0; ss < KSPLIT; ss++) {
    const float a = __expf(m[ss] - M);          // zero-trip split: weight 0
    den += l[ss] * a;
    const size_t i = ((size_t)(b * KSPLIT + ss) * TSEQ + t);
    const ushort4 u = *(const ushort4*)(OP + i * HS + d0);
    num.x += a * bf2f(u.x); num.y += a * bf2f(u.y);
    num.z += a * bf2f(u.z); num.w += a * bf2f(u.w);
  }
  const float inv = 1.f / den;
  *(float4*)(out + (size_t)row * HS + d0) =
      make_float4(num.x * inv, num.y * inv, num.z * inv, num.w * inv);
}

extern "C" void kernel_launch(void* const* d_in, const int* in_sizes, int n_in,
                              void* d_out, int out_size, void* d_ws, size_t ws_size,
                              hipStream_t stream) {
  const float* x  = (const float*)d_in[0];
  const float* Wq = (const float*)d_in[1];
  const float* Wk = (const float*)d_in[2];
  const float* Wv = (const float*)d_in[3];
  float* out = (float*)d_out;

  // ws: Wt 288K | q 2M | k 2M | vT 2M | ML 512K | OP 8M   (total ~15 MB)
  char* ws = (char*)d_ws;
  ushort_t* Wt = (ushort_t*)ws;
  ushort_t* qb = (ushort_t*)(ws + 294912);
  ushort_t* kb = (ushort_t*)(ws + 294912 + 2097152);
  ushort_t* vb = (ushort_t*)(ws + 294912 + 2 * 2097152);
  float*    ml = (float*)   (ws + 294912 + 3 * 2097152);
  ushort_t* op = (ushort_t*)(ws + 294912 + 3 * 2097152 + 524288);

  wprep<<<36, 256, 0, stream>>>(Wq, Wk, Wv, Wt);
  qkv_mfma<<<(NBATCH * TSEQ) / 32, 256, 0, stream>>>(x, Wt, qb, kb, vb);
  attn_part<<<64 * NBATCH * KSPLIT, 256, 0, stream>>>(qb, kb, vb, ml, op);
  attn_merge<<<1024, 256, 0, stream>>>(ml, op, out);
}